// Round 4
// baseline (278.407 us; speedup 1.0000x reference)
//
#include <hip/hip_runtime.h>
#include <hip/hip_bf16.h>

// BLAST factorized linear, two-kernel split with u intermediate in workspace:
//   K1: T[n, j*128+r] = sum_s X[n, j*256+s]*Vt[j,s,r]   (MFMA -> LDS, 1 barrier)
//       u[o][n][r]    = sum_j S[o,j,r]*T[n, j*128+r]    (VALU, 4-o-blocked) -> HBM (bf16)
//   K2: out[n, o*256+p] = bias + sum_r u[o][n][r]*U[o,r,p]  (MFMA, LDS-free, no barriers)

typedef __bf16 bf16x8 __attribute__((ext_vector_type(8)));
typedef __bf16 bf16x4 __attribute__((ext_vector_type(4)));
typedef float  f32x4  __attribute__((ext_vector_type(4)));

#define IN_DIM  4096
#define OUT_DIM 4096
#define NROWS   8192
#define BJ      16
#define BO      16
#define BS_IN   256
#define BS_OUT  256
#define RANK    128
#define TPAD    2056   // T_lds row stride (4112B = 257*16B: 16B-aligned, conflict-free)

__device__ __forceinline__ bf16x8 cvt8(f32x4 lo, f32x4 hi) {
  bf16x8 r;
  r[0] = (__bf16)lo[0]; r[1] = (__bf16)lo[1]; r[2] = (__bf16)lo[2]; r[3] = (__bf16)lo[3];
  r[4] = (__bf16)hi[0]; r[5] = (__bf16)hi[1]; r[6] = (__bf16)hi[2]; r[7] = (__bf16)hi[3];
  return r;
}
__device__ __forceinline__ bf16x4 cvt4(f32x4 v) {
  bf16x4 r;
  r[0] = (__bf16)v[0]; r[1] = (__bf16)v[1]; r[2] = (__bf16)v[2]; r[3] = (__bf16)v[3];
  return r;
}

// prep: Vt (16,256,128) fp32 -> vt_t[j][r][s] bf16 ; U (16,128,256) fp32 -> u_t[o][p][r] bf16
__global__ __launch_bounds__(256) void prep_kernel(
    const float* __restrict__ Vt, const float* __restrict__ U,
    __bf16* __restrict__ vt_t, __bf16* __restrict__ u_t)
{
  const int NV = BJ * RANK * BS_IN;   // 524288
  int idx = blockIdx.x * 256 + threadIdx.x;
  if (idx < NV) {
    int j = idx >> 15;
    int r = (idx >> 8) & (RANK - 1);
    int s = idx & (BS_IN - 1);
    vt_t[idx] = (__bf16)Vt[(j * BS_IN + s) * RANK + r];
  } else {
    int k = idx - NV;
    int o = k >> 15;
    int p = (k >> 7) & (BS_OUT - 1);
    int r = k & (RANK - 1);
    u_t[k] = (__bf16)U[(o * RANK + r) * BS_OUT + p];
  }
}

// ---------------- K1: build T (LDS) then fold with S -> u (HBM) ----------------
__global__ __launch_bounds__(512, 2) void k1_tfold(
    const float* __restrict__ x, const float* __restrict__ S,
    const __bf16* __restrict__ vt_t, __bf16* __restrict__ u_ws)
{
  __shared__ __bf16 T_lds[16 * TPAD];   // 65.7 KB

  const int tid  = threadIdx.x;
  const int lane = tid & 63;
  const int w    = tid >> 6;        // wave 0..7
  const int l15  = lane & 15;
  const int lhi  = lane >> 4;
  const size_t rowbase = (size_t)blockIdx.x * 16;

  // Stage A: wave handles j of parity (w&1), r-slice rs = (w>>1)*32.
  // Swapped MFMA: D=[r,n], lane -> (n=l15, r = rs + t*16 + lhi*4 + v).
  {
    const int jg = w & 1;
    const int rs = (w >> 1) * 32;
    const float* xrow = x + (rowbase + l15) * IN_DIM;
    for (int j = jg; j < BJ; j += 2) {
      f32x4 t0 = {0.f,0.f,0.f,0.f}, t1 = {0.f,0.f,0.f,0.f};
      const float*  xp = xrow + j * BS_IN;
      const __bf16* vb = vt_t + ((size_t)j * RANK + rs + l15) * BS_IN;
      #pragma unroll
      for (int ks = 0; ks < 8; ++ks) {            // K = 256 = 8*32
        const int kc = ks * 32 + lhi * 8;
        const f32x4 xlo = *(const f32x4*)(xp + kc);
        const f32x4 xhi = *(const f32x4*)(xp + kc + 4);
        const bf16x8 xb = cvt8(xlo, xhi);
        const bf16x8 a0 = *(const bf16x8*)(vb + kc);
        const bf16x8 a1 = *(const bf16x8*)(vb + 16 * BS_IN + kc);
        t0 = __builtin_amdgcn_mfma_f32_16x16x32_bf16(a0, xb, t0, 0, 0, 0);
        t1 = __builtin_amdgcn_mfma_f32_16x16x32_bf16(a1, xb, t1, 0, 0, 0);
      }
      *(bf16x4*)&T_lds[l15 * TPAD + j * RANK + rs + lhi * 4]      = cvt4(t0);
      *(bf16x4*)&T_lds[l15 * TPAD + j * RANK + rs + 16 + lhi * 4] = cvt4(t1);
    }
  }
  __syncthreads();

  // Fold: thread (rc = tid&15, fn = (tid>>4)&15, og = tid>>8).
  // Each thread: 2 blocks of 4 o's; reads each T element 2x total (not 16x).
  {
    const int rc = tid & 15;
    const int fn = (tid >> 4) & 15;
    const int og = tid >> 8;          // 0 or 1 -> o in [og*8, og*8+8)
    #pragma unroll
    for (int ob = 0; ob < 2; ++ob) {
      const int o0 = og * 8 + ob * 4;
      f32x4 accl[4], acch[4];
      #pragma unroll
      for (int oo = 0; oo < 4; ++oo) {
        accl[oo] = (f32x4){0.f,0.f,0.f,0.f};
        acch[oo] = (f32x4){0.f,0.f,0.f,0.f};
      }
      const float* sbase = S + (size_t)(o0 * BJ * RANK) + rc * 8;
      for (int j = 0; j < BJ; ++j) {
        const bf16x8 tv = *(const bf16x8*)&T_lds[fn * TPAD + j * RANK + rc * 8];
        const f32x4 tlo = {(float)tv[0], (float)tv[1], (float)tv[2], (float)tv[3]};
        const f32x4 thi = {(float)tv[4], (float)tv[5], (float)tv[6], (float)tv[7]};
        const float* sj = sbase + j * RANK;
        #pragma unroll
        for (int oo = 0; oo < 4; ++oo) {
          const f32x4 s0 = *(const f32x4*)(sj + oo * (BJ * RANK));
          const f32x4 s1 = *(const f32x4*)(sj + oo * (BJ * RANK) + 4);
          accl[oo] = s0 * tlo + accl[oo];
          acch[oo] = s1 * thi + acch[oo];
        }
      }
      #pragma unroll
      for (int oo = 0; oo < 4; ++oo) {
        const bf16x8 uw = cvt8(accl[oo], acch[oo]);
        *(bf16x8*)&u_ws[((size_t)(o0 + oo) * NROWS + rowbase + fn) * RANK + rc * 8] = uw;
      }
    }
  }
}

// ---------------- K2: out[n, o*256+p] = bias + u[o] @ U_o ----------------
// wg = 256 thr (4 waves), tile = 64 rows x 256 cols (one o). No LDS, no barriers.
__global__ __launch_bounds__(256, 4) void k2_out(
    const __bf16* __restrict__ u_ws, const __bf16* __restrict__ u_t,
    const float* __restrict__ bias, float* __restrict__ out)
{
  const int tid  = threadIdx.x;
  const int lane = tid & 63;
  const int w    = tid >> 6;        // wave -> row sub-tile
  const int l15  = lane & 15;
  const int lhi  = lane >> 4;
  const int o    = blockIdx.x >> 7;       // 0..15
  const int rt   = blockIdx.x & 127;      // 0..127
  const size_t nb = (size_t)rt * 64 + w * 16;

  // B-frags: u rows n = nb + l15
  const __bf16* ur = u_ws + ((size_t)o * NROWS + nb + l15) * RANK;
  bf16x8 ub[4];
  #pragma unroll
  for (int ks = 0; ks < 4; ++ks)
    ub[ks] = *(const bf16x8*)(ur + ks * 32 + lhi * 8);

  // A-frags: u_t rows p = o*256 + pf*16 + l15 ; D=[p,n] -> f32x4 stores
  const __bf16* ut = u_t + ((size_t)o * BS_OUT + l15) * RANK;
  f32x4 acc[16];
  #pragma unroll
  for (int pf = 0; pf < 16; ++pf) acc[pf] = (f32x4){0.f,0.f,0.f,0.f};
  #pragma unroll
  for (int pf = 0; pf < 16; ++pf) {
    #pragma unroll
    for (int ks = 0; ks < 4; ++ks) {
      const bf16x8 af = *(const bf16x8*)(ut + ((size_t)pf * 16) * RANK + ks * 32 + lhi * 8);
      acc[pf] = __builtin_amdgcn_mfma_f32_16x16x32_bf16(af, ub[ks], acc[pf], 0, 0, 0);
    }
  }
  float* orow = out + (nb + l15) * OUT_DIM + o * BS_OUT;
  #pragma unroll
  for (int pf = 0; pf < 16; ++pf) {
    const f32x4 bv = *(const f32x4*)(bias + o * BS_OUT + pf * 16 + lhi * 4);
    *(f32x4*)(orow + pf * 16 + lhi * 4) = acc[pf] + bv;
  }
}

extern "C" void kernel_launch(void* const* d_in, const int* in_sizes, int n_in,
                              void* d_out, int out_size, void* d_ws, size_t ws_size,
                              hipStream_t stream) {
  const float* x    = (const float*)d_in[0];
  const float* S    = (const float*)d_in[1];
  const float* U    = (const float*)d_in[2];
  const float* Vt   = (const float*)d_in[3];
  const float* bias = (const float*)d_in[4];
  float* out = (float*)d_out;

  __bf16* vt_t = (__bf16*)d_ws;                            // 1 MB
  __bf16* u_t  = vt_t + (size_t)BJ * RANK * BS_IN;         // 1 MB
  __bf16* u_ws = u_t + (size_t)BO * BS_OUT * RANK;         // 32 MB: u[o][n][r]

  const int prep_elems = BJ * RANK * BS_IN + BO * BS_OUT * RANK; // 1048576
  prep_kernel<<<prep_elems / 256, 256, 0, stream>>>(Vt, U, vt_t, u_t);
  k1_tfold<<<NROWS / 16, 512, 0, stream>>>(x, S, vt_t, u_ws);
  k2_out<<<(NROWS / 64) * BO, 256, 0, stream>>>(u_ws, u_t, bias, out);
}

// Round 5
// 184.071 us; speedup vs baseline: 1.5125x; 1.5125x over previous
//
#include <hip/hip_runtime.h>
#include <hip/hip_bf16.h>

// BLAST factorized linear, 3 kernels, all global MFMA-operand loads coalesced
// via fragment-order layouts built in prep:
//   K1: T[n, j*128+r] = sum_s X[n, j*256+s]*Vt[j,s,r]   (per-j GEMM, X via LDS)
//   K2: u[n,r] = sum_j S[o,j,r]*T[n,j*128+r] (VALU, T tile in LDS once)
//       out[n, o*256+p] = bias + u @ U_o               (MFMA, ut_frag coalesced)

typedef __bf16 bf16x8 __attribute__((ext_vector_type(8)));
typedef __bf16 bf16x4 __attribute__((ext_vector_type(4)));
typedef float  f32x4  __attribute__((ext_vector_type(4)));

#define IN_DIM  4096
#define OUT_DIM 4096
#define NROWS   8192
#define BJ      16
#define BO      16
#define RANK    128

__device__ __forceinline__ bf16x4 cvt4(f32x4 v) {
  bf16x4 r;
  r[0] = (__bf16)v[0]; r[1] = (__bf16)v[1]; r[2] = (__bf16)v[2]; r[3] = (__bf16)v[3];
  return r;
}

// ---- prep: build fragment-order weights ----
// vt_frag[(((j*8+rf)*8+ks)*64 + lane)*8 + e] = Vt[j][s=ks*32+(lane>>4)*8+e][r=rf*16+(lane&15)]
// ut_frag[(((o*16+pf)*4+ks)*64 + lane)*8 + e] = U[o][r=ks*32+(lane>>4)*8+e][p=pf*16+(lane&15)]
__global__ __launch_bounds__(256) void prep_frag(
    const float* __restrict__ Vt, const float* __restrict__ U,
    __bf16* __restrict__ vtf, __bf16* __restrict__ utf)
{
  const int NV = BJ * 256 * RANK;   // 524288
  int idx = blockIdx.x * 256 + threadIdx.x;
  if (idx < NV) {
    // Vt layout [16][256][128]
    int j = idx >> 15, s = (idx >> 7) & 255, r = idx & 127;
    int rf = r >> 4, l = r & 15, ks = s >> 5, lh = (s >> 3) & 3, e = s & 7;
    vtf[((((j * 8 + rf) * 8 + ks) * 64 + lh * 16 + l) << 3) + e] = (__bf16)Vt[idx];
  } else {
    // U layout [16][128][256]
    int k = idx - NV;
    int o = k >> 15, r = (k >> 8) & 127, p = k & 255;
    int pf = p >> 4, l = p & 15, ks = r >> 5, lh = (r >> 3) & 3, e = r & 7;
    utf[((((o * 16 + pf) * 4 + ks) * 64 + lh * 16 + l) << 3) + e] = (__bf16)U[k];
  }
}

// ---- K1: T-tile GEMM. wg=256 (4 waves), tile 64 rows x 128 r, one j. ----
__global__ __launch_bounds__(256, 4) void k1_T(
    const float* __restrict__ x, const __bf16* __restrict__ vtf,
    __bf16* __restrict__ T)
{
  __shared__ __bf16 X_lds[64 * 256];   // 32 KB, 16B-chunk index XOR row&15

  const int tid  = threadIdx.x;
  const int lane = tid & 63;
  const int w    = tid >> 6;
  const int l15  = lane & 15;
  const int lhi  = lane >> 4;
  const int mt   = blockIdx.x >> 4;
  const int j    = blockIdx.x & 15;
  const size_t rowbase = (size_t)mt * 64;

  // stage X: one full row (1KB) per wave-instruction, fully coalesced
  #pragma unroll
  for (int i = 0; i < 16; ++i) {
    const int row = w * 16 + i;
    const f32x4 v = *(const f32x4*)(x + (rowbase + row) * IN_DIM + j * 256 + lane * 4);
    const int c = (lane >> 1) ^ (row & 15);             // 16B chunk 0..31
    *(bf16x4*)&X_lds[row * 256 + c * 8 + (lane & 1) * 4] = cvt4(v);
  }
  __syncthreads();

  // wave w computes r rows [w*32, w*32+32) for all 64 n
  f32x4 acc[2][4];
  #pragma unroll
  for (int a = 0; a < 2; ++a)
    #pragma unroll
    for (int b = 0; b < 4; ++b) acc[a][b] = (f32x4){0.f, 0.f, 0.f, 0.f};

  const __bf16* va = vtf + ((size_t)(j * 8 + w * 2) * 8) * 512 + lane * 8;
  #pragma unroll
  for (int ks = 0; ks < 8; ++ks) {
    bf16x8 bfr[4];
    #pragma unroll
    for (int nf = 0; nf < 4; ++nf) {
      const int c = (ks * 4 + lhi) ^ l15;
      bfr[nf] = *(const bf16x8*)&X_lds[(nf * 16 + l15) * 256 + c * 8];
    }
    const bf16x8 a0 = *(const bf16x8*)(va + (size_t)ks * 512);
    const bf16x8 a1 = *(const bf16x8*)(va + (size_t)(8 + ks) * 512);
    #pragma unroll
    for (int nf = 0; nf < 4; ++nf) {
      acc[0][nf] = __builtin_amdgcn_mfma_f32_16x16x32_bf16(a0, bfr[nf], acc[0][nf], 0, 0, 0);
      acc[1][nf] = __builtin_amdgcn_mfma_f32_16x16x32_bf16(a1, bfr[nf], acc[1][nf], 0, 0, 0);
    }
  }
  // store: D=[r,n] -> lane holds 4 consecutive r for row n = nf*16+l15
  #pragma unroll
  for (int rfi = 0; rfi < 2; ++rfi)
    #pragma unroll
    for (int nf = 0; nf < 4; ++nf) {
      *(bf16x4*)&T[(rowbase + nf * 16 + l15) * 2048 + j * RANK + (w * 2 + rfi) * 16 + lhi * 4]
          = cvt4(acc[rfi][nf]);
    }
}

// ---- K2: fold + out. wg=256 (4 waves), 16 rows, loop o. ----
__global__ __launch_bounds__(256, 2) void k2_out(
    const __bf16* __restrict__ T, const float* __restrict__ S,
    const __bf16* __restrict__ utf, const float* __restrict__ bias,
    float* __restrict__ out)
{
  __shared__ __bf16 T_lds[16 * 2048];    // 64 KB, 16B-chunk XOR row&15
  __shared__ __bf16 u_lds[2][16 * 128];  // 2 x 4 KB, chunk XOR row

  const int tid  = threadIdx.x;
  const int lane = tid & 63;
  const int w    = tid >> 6;
  const int l15  = lane & 15;
  const int lhi  = lane >> 4;
  const size_t rowbase = (size_t)blockIdx.x * 16;

  // stage T tile: 1KB coalesced per wave-instruction
  #pragma unroll
  for (int i = 0; i < 16; ++i) {
    const int row = w * 4 + (i >> 2), q = i & 3;
    const bf16x8 v = *(const bf16x8*)(T + (rowbase + row) * 2048 + q * 512 + lane * 8);
    const int c = (q * 64 + lane) ^ (row & 15);         // chunk 0..255
    *(bf16x8*)&T_lds[row * 2048 + c * 8] = v;
  }
  __syncthreads();

  const int fn = tid >> 4;    // fold row 0..15
  const int rc = tid & 15;    // fold r-chunk (8 r)

  for (int o = 0; o < BO; ++o) {
    // fold: u[fn][rc*8..+8] = sum_j S[o,j,r] * T[fn][j*128+r]
    f32x4 ua = {0.f,0.f,0.f,0.f}, ub = {0.f,0.f,0.f,0.f};
    const float* sp = S + (size_t)(o * BJ) * RANK + rc * 8;
    #pragma unroll
    for (int jj = 0; jj < BJ; ++jj) {
      const int c = (jj * 16 + rc) ^ fn;
      const bf16x8 tv = *(const bf16x8*)&T_lds[fn * 2048 + c * 8];
      const f32x4 s0 = *(const f32x4*)(sp + jj * RANK);
      const f32x4 s1 = *(const f32x4*)(sp + jj * RANK + 4);
      const f32x4 tlo = {(float)tv[0], (float)tv[1], (float)tv[2], (float)tv[3]};
      const f32x4 thi = {(float)tv[4], (float)tv[5], (float)tv[6], (float)tv[7]};
      ua = s0 * tlo + ua;
      ub = s1 * thi + ub;
    }
    {
      bf16x8 uw;
      uw[0]=(__bf16)ua[0]; uw[1]=(__bf16)ua[1]; uw[2]=(__bf16)ua[2]; uw[3]=(__bf16)ua[3];
      uw[4]=(__bf16)ub[0]; uw[5]=(__bf16)ub[1]; uw[6]=(__bf16)ub[2]; uw[7]=(__bf16)ub[3];
      *(bf16x8*)&u_lds[o & 1][fn * 128 + ((rc ^ fn)) * 8] = uw;
    }
    __syncthreads();

    // out tile: wave w covers p = [w*64, w*64+64)
    bf16x8 ubf[4];
    #pragma unroll
    for (int ks = 0; ks < 4; ++ks) {
      const int c = (ks * 4 + lhi) ^ l15;
      ubf[ks] = *(const bf16x8*)&u_lds[o & 1][l15 * 128 + c * 8];
    }
    const __bf16* uab = utf + ((size_t)(o * 16 + w * 4) * 4) * 512 + lane * 8;
    f32x4 acc[4];
    #pragma unroll
    for (int pi = 0; pi < 4; ++pi) acc[pi] = (f32x4){0.f,0.f,0.f,0.f};
    #pragma unroll
    for (int pi = 0; pi < 4; ++pi)
      #pragma unroll
      for (int ks = 0; ks < 4; ++ks)
        acc[pi] = __builtin_amdgcn_mfma_f32_16x16x32_bf16(
            *(const bf16x8*)(uab + (size_t)(pi * 4 + ks) * 512), ubf[ks], acc[pi], 0, 0, 0);
    #pragma unroll
    for (int pi = 0; pi < 4; ++pi) {
      const int col = o * 256 + (w * 4 + pi) * 16 + lhi * 4;
      const f32x4 bv = *(const f32x4*)(bias + col);
      *(f32x4*)(out + (rowbase + l15) * OUT_DIM + col) = acc[pi] + bv;
    }
    // dbuf: next fold writes the other buffer; no trailing barrier needed
  }
}

extern "C" void kernel_launch(void* const* d_in, const int* in_sizes, int n_in,
                              void* d_out, int out_size, void* d_ws, size_t ws_size,
                              hipStream_t stream) {
  const float* x    = (const float*)d_in[0];
  const float* S    = (const float*)d_in[1];
  const float* U    = (const float*)d_in[2];
  const float* Vt   = (const float*)d_in[3];
  const float* bias = (const float*)d_in[4];
  float* out = (float*)d_out;

  __bf16* vtf = (__bf16*)d_ws;                       // 1 MB
  __bf16* utf = vtf + (size_t)BJ * 8 * 8 * 512;      // 1 MB
  __bf16* T   = utf + (size_t)BO * 16 * 4 * 512;     // 32 MB: T[8192][2048]

  prep_frag<<<(2 * 524288) / 256, 256, 0, stream>>>(Vt, U, vtf, utf);
  k1_T<<<(NROWS / 64) * BJ, 256, 0, stream>>>(x, vtf, T);
  k2_out<<<NROWS / 16, 256, 0, stream>>>(T, S, utf, bias, out);
}

// Round 6
// 163.836 us; speedup vs baseline: 1.6993x; 1.1235x over previous
//
#include <hip/hip_runtime.h>
#include <hip/hip_bf16.h>

// BLAST factorized linear, 3 kernels:
//   K1: T[n, j*128+r] = sum_s X[n, j*256+s]*Vt[j,s,r]  (per-j GEMM, frag-order Vt)
//   K2: fold u[o][n][r] = sum_j S[o,j,r]*T[n,j*128+r]  (VALU, T direct from global,
//       uacc[16] in regs) -> u_lds (1 barrier) -> out = bias + u @ U_o (MFMA,
//       wave-private o pair, frag-order U, f32x4 stores). No other barriers.

typedef __bf16 bf16x8 __attribute__((ext_vector_type(8)));
typedef __bf16 bf16x4 __attribute__((ext_vector_type(4)));
typedef float  f32x4  __attribute__((ext_vector_type(4)));

#define IN_DIM  4096
#define OUT_DIM 4096
#define NROWS   8192
#define BJ      16
#define BO      16
#define RANK    128

__device__ __forceinline__ bf16x4 cvt4(f32x4 v) {
  bf16x4 r;
  r[0] = (__bf16)v[0]; r[1] = (__bf16)v[1]; r[2] = (__bf16)v[2]; r[3] = (__bf16)v[3];
  return r;
}

// ---- prep: build fragment-order weights ----
// vt_frag[(((j*8+rf)*8+ks)*64 + lane)*8 + e] = Vt[j][s=ks*32+(lane>>4)*8+e][r=rf*16+(lane&15)]
// ut_frag[(((o*16+pf)*4+ks)*64 + lane)*8 + e] = U[o][r=ks*32+(lane>>4)*8+e][p=pf*16+(lane&15)]
__global__ __launch_bounds__(256) void prep_frag(
    const float* __restrict__ Vt, const float* __restrict__ U,
    __bf16* __restrict__ vtf, __bf16* __restrict__ utf)
{
  const int NV = BJ * 256 * RANK;   // 524288
  int idx = blockIdx.x * 256 + threadIdx.x;
  if (idx < NV) {
    int j = idx >> 15, s = (idx >> 7) & 255, r = idx & 127;
    int rf = r >> 4, l = r & 15, ks = s >> 5, lh = (s >> 3) & 3, e = s & 7;
    vtf[((((j * 8 + rf) * 8 + ks) * 64 + lh * 16 + l) << 3) + e] = (__bf16)Vt[idx];
  } else {
    int k = idx - NV;
    int o = k >> 15, r = (k >> 8) & 127, p = k & 255;
    int pf = p >> 4, l = p & 15, ks = r >> 5, lh = (r >> 3) & 3, e = r & 7;
    utf[((((o * 16 + pf) * 4 + ks) * 64 + lh * 16 + l) << 3) + e] = (__bf16)U[k];
  }
}

// ---- K1: T-tile GEMM. wg=256 (4 waves), tile 64 rows x 128 r, one j. ----
__global__ __launch_bounds__(256, 4) void k1_T(
    const float* __restrict__ x, const __bf16* __restrict__ vtf,
    __bf16* __restrict__ T)
{
  __shared__ __bf16 X_lds[64 * 256];   // 32 KB, 16B-chunk index XOR row&15

  const int tid  = threadIdx.x;
  const int lane = tid & 63;
  const int w    = tid >> 6;
  const int l15  = lane & 15;
  const int lhi  = lane >> 4;
  const int mt   = blockIdx.x >> 4;
  const int j    = blockIdx.x & 15;
  const size_t rowbase = (size_t)mt * 64;

  #pragma unroll
  for (int i = 0; i < 16; ++i) {
    const int row = w * 16 + i;
    const f32x4 v = *(const f32x4*)(x + (rowbase + row) * IN_DIM + j * 256 + lane * 4);
    const int c = (lane >> 1) ^ (row & 15);
    *(bf16x4*)&X_lds[row * 256 + c * 8 + (lane & 1) * 4] = cvt4(v);
  }
  __syncthreads();

  f32x4 acc[2][4];
  #pragma unroll
  for (int a = 0; a < 2; ++a)
    #pragma unroll
    for (int b = 0; b < 4; ++b) acc[a][b] = (f32x4){0.f, 0.f, 0.f, 0.f};

  const __bf16* va = vtf + ((size_t)(j * 8 + w * 2) * 8) * 512 + lane * 8;
  #pragma unroll
  for (int ks = 0; ks < 8; ++ks) {
    bf16x8 bfr[4];
    #pragma unroll
    for (int nf = 0; nf < 4; ++nf) {
      const int c = (ks * 4 + lhi) ^ l15;
      bfr[nf] = *(const bf16x8*)&X_lds[(nf * 16 + l15) * 256 + c * 8];
    }
    const bf16x8 a0 = *(const bf16x8*)(va + (size_t)ks * 512);
    const bf16x8 a1 = *(const bf16x8*)(va + (size_t)(8 + ks) * 512);
    #pragma unroll
    for (int nf = 0; nf < 4; ++nf) {
      acc[0][nf] = __builtin_amdgcn_mfma_f32_16x16x32_bf16(a0, bfr[nf], acc[0][nf], 0, 0, 0);
      acc[1][nf] = __builtin_amdgcn_mfma_f32_16x16x32_bf16(a1, bfr[nf], acc[1][nf], 0, 0, 0);
    }
  }
  #pragma unroll
  for (int rfi = 0; rfi < 2; ++rfi)
    #pragma unroll
    for (int nf = 0; nf < 4; ++nf) {
      *(bf16x4*)&T[(rowbase + nf * 16 + l15) * 2048 + j * RANK + (w * 2 + rfi) * 16 + lhi * 4]
          = cvt4(acc[rfi][nf]);
    }
}

// ---- K2: fold (global T, reg acc) -> u_lds -> MFMA out. wg=512, 16 rows. ----
__global__ __launch_bounds__(512, 4) void k2_out(
    const __bf16* __restrict__ T, const float* __restrict__ S,
    const __bf16* __restrict__ utf, const float* __restrict__ bias,
    float* __restrict__ out)
{
  __shared__ __bf16 u_lds[BO * 16 * RANK];   // 64 KB: [o][n][r], 16B chunk ^ n

  const int tid  = threadIdx.x;
  const int lane = tid & 63;
  const int w    = tid >> 6;          // wave 0..7
  const size_t rowbase = (size_t)blockIdx.x * 16;

  // ---- fold: thread = (n = tid>>5, rc4 = tid&31 -> r = rc4*4..+4) ----
  {
    const int rc4 = tid & 31;
    const int n   = tid >> 5;
    f32x4 uacc[BO];
    #pragma unroll
    for (int o = 0; o < BO; ++o) uacc[o] = (f32x4){0.f, 0.f, 0.f, 0.f};

    const __bf16* tp = T + (rowbase + n) * 2048 + rc4 * 4;
    const float*  sp = S + rc4 * 4;
    #pragma unroll 2
    for (int j = 0; j < BJ; ++j) {
      const bf16x4 tv4 = *(const bf16x4*)(tp + j * RANK);
      const f32x4 tv = {(float)tv4[0], (float)tv4[1], (float)tv4[2], (float)tv4[3]};
      #pragma unroll
      for (int o = 0; o < BO; ++o) {
        const f32x4 sv = *(const f32x4*)(sp + (size_t)(o * BJ + j) * RANK);
        uacc[o] = sv * tv + uacc[o];
      }
    }
    const int c = (rc4 >> 1) ^ n;       // swizzled 16B chunk
    const int h = (rc4 & 1) * 4;
    #pragma unroll
    for (int o = 0; o < BO; ++o) {
      *(bf16x4*)&u_lds[(size_t)(o * 16 + n) * RANK + c * 8 + h] = cvt4(uacc[o]);
    }
  }
  __syncthreads();

  // ---- MFMA: wave w -> o = 2w, 2w+1 ; no barriers ----
  const int l15 = lane & 15;
  const int lhi = lane >> 4;
  #pragma unroll
  for (int q = 0; q < 2; ++q) {
    const int o = w * 2 + q;
    bf16x8 ubf[4];
    #pragma unroll
    for (int ks = 0; ks < 4; ++ks) {
      const int c = (ks * 4 + lhi) ^ l15;
      ubf[ks] = *(const bf16x8*)&u_lds[(size_t)(o * 16 + l15) * RANK + c * 8];
    }
    const __bf16* uab = utf + (size_t)(o * 16) * 4 * 512 + lane * 8;
    f32x4 acc[16];
    #pragma unroll
    for (int pf = 0; pf < 16; ++pf) acc[pf] = (f32x4){0.f, 0.f, 0.f, 0.f};
    #pragma unroll
    for (int pf = 0; pf < 16; ++pf) {
      #pragma unroll
      for (int ks = 0; ks < 4; ++ks) {
        const bf16x8 af = *(const bf16x8*)(uab + (size_t)(pf * 4 + ks) * 512);
        acc[pf] = __builtin_amdgcn_mfma_f32_16x16x32_bf16(af, ubf[ks], acc[pf], 0, 0, 0);
      }
    }
    float* orow = out + (rowbase + l15) * OUT_DIM + o * 256;
    #pragma unroll
    for (int pf = 0; pf < 16; ++pf) {
      const f32x4 bv = *(const f32x4*)(bias + o * 256 + pf * 16 + lhi * 4);
      *(f32x4*)(orow + pf * 16 + lhi * 4) = acc[pf] + bv;
    }
  }
}

extern "C" void kernel_launch(void* const* d_in, const int* in_sizes, int n_in,
                              void* d_out, int out_size, void* d_ws, size_t ws_size,
                              hipStream_t stream) {
  const float* x    = (const float*)d_in[0];
  const float* S    = (const float*)d_in[1];
  const float* U    = (const float*)d_in[2];
  const float* Vt   = (const float*)d_in[3];
  const float* bias = (const float*)d_in[4];
  float* out = (float*)d_out;

  __bf16* vtf = (__bf16*)d_ws;                       // 1 MB
  __bf16* utf = vtf + (size_t)BJ * 8 * 8 * 512;      // 1 MB
  __bf16* T   = utf + (size_t)BO * 16 * 4 * 512;     // 32 MB: T[8192][2048]

  prep_frag<<<(2 * 524288) / 256, 256, 0, stream>>>(Vt, U, vtf, utf);
  k1_T<<<(NROWS / 64) * BJ, 256, 0, stream>>>(x, vtf, T);
  k2_out<<<NROWS / 16, 512, 0, stream>>>(T, S, utf, bias, out);
}

// Round 7
// 145.345 us; speedup vs baseline: 1.9155x; 1.1272x over previous
//
#include <hip/hip_runtime.h>
#include <hip/hip_bf16.h>

// BLAST factorized linear, 4 kernels, each phase-ideal:
//   prep: frag-order weights vtf/utf
//   K1 : T[n, j*128+r] = sum_s X[n,j*256+s]*Vt[j,s,r]   (GEMM, X via LDS)
//   K2a: u[o][n][r] = sum_j S[o,j,r]*T[n,j*128+r]       (VALU fold, no LDS,
//        T in regs, o in 4 blocks of 4 -> 16-reg acc, S loads L2-broadcast)
//   K2b: out[n, o*256+p] = bias + u[o] @ U_o            (GEMM, u via LDS)

typedef __bf16 bf16x8 __attribute__((ext_vector_type(8)));
typedef __bf16 bf16x4 __attribute__((ext_vector_type(4)));
typedef float  f32x4  __attribute__((ext_vector_type(4)));

#define IN_DIM  4096
#define OUT_DIM 4096
#define NROWS   8192
#define BJ      16
#define BO      16
#define RANK    128

__device__ __forceinline__ bf16x4 cvt4(f32x4 v) {
  bf16x4 r;
  r[0] = (__bf16)v[0]; r[1] = (__bf16)v[1]; r[2] = (__bf16)v[2]; r[3] = (__bf16)v[3];
  return r;
}

// ---- prep: build fragment-order weights ----
// vtf[(((j*8+rf)*8+ks)*64 + lane)*8 + e] = Vt[j][s=ks*32+(lane>>4)*8+e][r=rf*16+(lane&15)]
// utf[(((o*16+pf)*4+ks)*64 + lane)*8 + e] = U[o][r=ks*32+(lane>>4)*8+e][p=pf*16+(lane&15)]
__global__ __launch_bounds__(256) void prep_frag(
    const float* __restrict__ Vt, const float* __restrict__ U,
    __bf16* __restrict__ vtf, __bf16* __restrict__ utf)
{
  const int NV = BJ * 256 * RANK;   // 524288
  int idx = blockIdx.x * 256 + threadIdx.x;
  if (idx < NV) {
    int j = idx >> 15, s = (idx >> 7) & 255, r = idx & 127;
    int rf = r >> 4, l = r & 15, ks = s >> 5, lh = (s >> 3) & 3, e = s & 7;
    vtf[((((j * 8 + rf) * 8 + ks) * 64 + lh * 16 + l) << 3) + e] = (__bf16)Vt[idx];
  } else {
    int k = idx - NV;
    int o = k >> 15, r = (k >> 8) & 127, p = k & 255;
    int pf = p >> 4, l = p & 15, ks = r >> 5, lh = (r >> 3) & 3, e = r & 7;
    utf[((((o * 16 + pf) * 4 + ks) * 64 + lh * 16 + l) << 3) + e] = (__bf16)U[k];
  }
}

// ---- K1: T-tile GEMM. wg=256 (4 waves), tile 64 rows x 128 r, one j. ----
__global__ __launch_bounds__(256, 4) void k1_T(
    const float* __restrict__ x, const __bf16* __restrict__ vtf,
    __bf16* __restrict__ T)
{
  __shared__ __bf16 X_lds[64 * 256];   // 32 KB, 16B-chunk index XOR row&15

  const int tid  = threadIdx.x;
  const int lane = tid & 63;
  const int w    = tid >> 6;
  const int l15  = lane & 15;
  const int lhi  = lane >> 4;
  const int mt   = blockIdx.x >> 4;
  const int j    = blockIdx.x & 15;
  const size_t rowbase = (size_t)mt * 64;

  #pragma unroll
  for (int i = 0; i < 16; ++i) {
    const int row = w * 16 + i;
    const f32x4 v = *(const f32x4*)(x + (rowbase + row) * IN_DIM + j * 256 + lane * 4);
    const int c = (lane >> 1) ^ (row & 15);
    *(bf16x4*)&X_lds[row * 256 + c * 8 + (lane & 1) * 4] = cvt4(v);
  }
  __syncthreads();

  f32x4 acc[2][4];
  #pragma unroll
  for (int a = 0; a < 2; ++a)
    #pragma unroll
    for (int b = 0; b < 4; ++b) acc[a][b] = (f32x4){0.f, 0.f, 0.f, 0.f};

  const __bf16* va = vtf + ((size_t)(j * 8 + w * 2) * 8) * 512 + lane * 8;
  #pragma unroll
  for (int ks = 0; ks < 8; ++ks) {
    bf16x8 bfr[4];
    #pragma unroll
    for (int nf = 0; nf < 4; ++nf) {
      const int c = (ks * 4 + lhi) ^ l15;
      bfr[nf] = *(const bf16x8*)&X_lds[(nf * 16 + l15) * 256 + c * 8];
    }
    const bf16x8 a0 = *(const bf16x8*)(va + (size_t)ks * 512);
    const bf16x8 a1 = *(const bf16x8*)(va + (size_t)(8 + ks) * 512);
    #pragma unroll
    for (int nf = 0; nf < 4; ++nf) {
      acc[0][nf] = __builtin_amdgcn_mfma_f32_16x16x32_bf16(a0, bfr[nf], acc[0][nf], 0, 0, 0);
      acc[1][nf] = __builtin_amdgcn_mfma_f32_16x16x32_bf16(a1, bfr[nf], acc[1][nf], 0, 0, 0);
    }
  }
  #pragma unroll
  for (int rfi = 0; rfi < 2; ++rfi)
    #pragma unroll
    for (int nf = 0; nf < 4; ++nf) {
      *(bf16x4*)&T[(rowbase + nf * 16 + l15) * 2048 + j * RANK + (w * 2 + rfi) * 16 + lhi * 4]
          = cvt4(acc[rfi][nf]);
    }
}

// ---- K2a: fold only. wg=512, no LDS, no barriers. 16 rows per wg. ----
// thread: n = tid&15 (lane-fast -> S uniform over n), rc = tid>>4 (r = rc*4).
__global__ __launch_bounds__(512, 4) void k2a_fold(
    const __bf16* __restrict__ T, const float* __restrict__ S,
    __bf16* __restrict__ u_ws)
{
  const int tid = threadIdx.x;
  const int n   = tid & 15;
  const int rc  = tid >> 4;                 // 0..31
  const size_t rowbase = (size_t)blockIdx.x * 16;

  // T slice in regs: 16 j x bf16x4 (32 VGPR)
  bf16x4 tr[BJ];
  const __bf16* tp = T + (rowbase + n) * 2048 + rc * 4;
  #pragma unroll
  for (int j = 0; j < BJ; ++j) tr[j] = *(const bf16x4*)(tp + j * RANK);

  #pragma unroll
  for (int ob = 0; ob < 4; ++ob) {
    f32x4 acc0 = {0.f,0.f,0.f,0.f}, acc1 = {0.f,0.f,0.f,0.f};
    f32x4 acc2 = {0.f,0.f,0.f,0.f}, acc3 = {0.f,0.f,0.f,0.f};
    const float* sp = S + (size_t)(ob * 4 * BJ) * RANK + rc * 4;
    #pragma unroll
    for (int j = 0; j < BJ; ++j) {
      const f32x4 tv = {(float)tr[j][0], (float)tr[j][1], (float)tr[j][2], (float)tr[j][3]};
      const f32x4 s0 = *(const f32x4*)(sp + (size_t)(0 * BJ + j) * RANK);
      const f32x4 s1 = *(const f32x4*)(sp + (size_t)(1 * BJ + j) * RANK);
      const f32x4 s2 = *(const f32x4*)(sp + (size_t)(2 * BJ + j) * RANK);
      const f32x4 s3 = *(const f32x4*)(sp + (size_t)(3 * BJ + j) * RANK);
      acc0 = s0 * tv + acc0;
      acc1 = s1 * tv + acc1;
      acc2 = s2 * tv + acc2;
      acc3 = s3 * tv + acc3;
    }
    __bf16* up = u_ws + ((size_t)(ob * 4) * NROWS + rowbase + n) * RANK + rc * 4;
    *(bf16x4*)(up + 0 * NROWS * RANK) = cvt4(acc0);
    *(bf16x4*)(up + 1 * NROWS * RANK) = cvt4(acc1);
    *(bf16x4*)(up + 2 * NROWS * RANK) = cvt4(acc2);
    *(bf16x4*)(up + 3 * NROWS * RANK) = cvt4(acc3);
  }
}

// ---- K2b: out GEMM. wg=256 (4 waves), tile 64 rows x 256 p, one o. ----
__global__ __launch_bounds__(256, 4) void k2b_gemm(
    const __bf16* __restrict__ u_ws, const __bf16* __restrict__ utf,
    const float* __restrict__ bias, float* __restrict__ out)
{
  __shared__ __bf16 u_lds[64 * 128];   // 16 KB, 16B-chunk index XOR row&15

  const int tid  = threadIdx.x;
  const int lane = tid & 63;
  const int w    = tid >> 6;
  const int l15  = lane & 15;
  const int lhi  = lane >> 4;
  const int o    = blockIdx.x & 15;
  const int mt   = blockIdx.x >> 4;
  const size_t rowbase = (size_t)mt * 64;

  // stage u tile: 64 rows x 256B, coalesced (4 rows/instr)
  #pragma unroll
  for (int i = 0; i < 4; ++i) {
    const int row = i * 16 + (tid >> 4);
    const bf16x8 v = *(const bf16x8*)(
        u_ws + ((size_t)o * NROWS + rowbase + row) * RANK + (tid & 15) * 8);
    const int c = (tid & 15) ^ (row & 15);
    *(bf16x8*)&u_lds[row * RANK + c * 8] = v;
  }
  __syncthreads();

  // wave w: p = w*64 .. +64 ; D=[p,n]
  f32x4 acc[4][4];   // [pi][nf]
  #pragma unroll
  for (int a = 0; a < 4; ++a)
    #pragma unroll
    for (int b = 0; b < 4; ++b) acc[a][b] = (f32x4){0.f, 0.f, 0.f, 0.f};

  #pragma unroll
  for (int ks = 0; ks < 4; ++ks) {
    bf16x8 ubf[4];
    #pragma unroll
    for (int nf = 0; nf < 4; ++nf) {
      const int c = (ks * 4 + lhi) ^ l15;
      ubf[nf] = *(const bf16x8*)&u_lds[(nf * 16 + l15) * RANK + c * 8];
    }
    #pragma unroll
    for (int pi = 0; pi < 4; ++pi) {
      const bf16x8 af = *(const bf16x8*)(
          utf + ((size_t)((o * 16 + w * 4 + pi) * 4 + ks)) * 512 + lane * 8);
      #pragma unroll
      for (int nf = 0; nf < 4; ++nf)
        acc[pi][nf] = __builtin_amdgcn_mfma_f32_16x16x32_bf16(af, ubf[nf], acc[pi][nf], 0, 0, 0);
    }
  }

  #pragma unroll
  for (int pi = 0; pi < 4; ++pi) {
    const int colb = o * 256 + (w * 4 + pi) * 16 + lhi * 4;
    const f32x4 bv = *(const f32x4*)(bias + colb);
    #pragma unroll
    for (int nf = 0; nf < 4; ++nf) {
      *(f32x4*)(out + (rowbase + nf * 16 + l15) * OUT_DIM + colb) = acc[pi][nf] + bv;
    }
  }
}

extern "C" void kernel_launch(void* const* d_in, const int* in_sizes, int n_in,
                              void* d_out, int out_size, void* d_ws, size_t ws_size,
                              hipStream_t stream) {
  const float* x    = (const float*)d_in[0];
  const float* S    = (const float*)d_in[1];
  const float* U    = (const float*)d_in[2];
  const float* Vt   = (const float*)d_in[3];
  const float* bias = (const float*)d_in[4];
  float* out = (float*)d_out;

  __bf16* vtf  = (__bf16*)d_ws;                        // 1 MB
  __bf16* utf  = vtf + (size_t)BJ * 8 * 8 * 512;       // 1 MB
  __bf16* T    = utf + (size_t)BO * 16 * 4 * 512;      // 32 MB: T[8192][2048]
  __bf16* u_ws = T + (size_t)NROWS * 2048;             // 32 MB: u[16][8192][128]

  prep_frag<<<(2 * 524288) / 256, 256, 0, stream>>>(Vt, U, vtf, utf);
  k1_T<<<(NROWS / 64) * BJ, 256, 0, stream>>>(x, vtf, T);
  k2a_fold<<<NROWS / 16, 512, 0, stream>>>(T, S, u_ws);
  k2b_gemm<<<(NROWS / 64) * BO, 256, 0, stream>>>(u_ws, utf, bias, out);
}